// Round 3
// baseline (273.269 us; speedup 1.0000x reference)
//
#include <hip/hip_runtime.h>

// Problem constants: x [4, 64, 64, 128] fp32
constexpr int C       = 128;
constexpr int N       = 4096;
constexpr int BATCH   = 4;
constexpr int TOTROWS = BATCH * N;            // 16384
constexpr float SCALE = 0.08838834764831845f; // 1/sqrt(128)

constexpr int BK   = 64;     // keys per tile
constexpr int KSTR = 136;    // kl stride (bf16 elems): 272 B rows, 16B-aligned, 8-lane b128 groups conflict-free
constexpr int VSTR = 72;     // vl stride: 144 B rows
constexpr int PSTR = 72;     // pl stride: 144 B rows

typedef __attribute__((ext_vector_type(8))) short bf16x8;
typedef __attribute__((ext_vector_type(4))) float f32x4;

__device__ inline unsigned short f2bf(float f) {   // RNE float->bf16
    unsigned int u = __float_as_uint(f);
    return (unsigned short)((u + 0x7FFFu + ((u >> 16) & 1u)) >> 16);
}
__device__ inline unsigned int pack2bf(float a, float b) {
    return (unsigned int)f2bf(a) | ((unsigned int)f2bf(b) << 16);
}
__device__ inline float bf2f(unsigned short u) {
    return __uint_as_float((unsigned int)u << 16);
}

// ---------------------------------------------------------------------------
// prep: blocks 0..255 convert x fp32 -> xb bf16; blocks 256..258 build
// Wt[mat][o][i] = W[mat][i][o] (bf16, SCALE folded into mat 0) + bias fp32.
// ---------------------------------------------------------------------------
__global__ __launch_bounds__(256)
void prep_kernel(const float* __restrict__ x,
                 const float* __restrict__ Wq, const float* __restrict__ bq,
                 const float* __restrict__ Wk, const float* __restrict__ bk,
                 const float* __restrict__ Wv, const float* __restrict__ bv,
                 unsigned short* __restrict__ xb,
                 unsigned short* __restrict__ Wt,
                 float* __restrict__ bprep)
{
    const int tid = threadIdx.x;
    const int bx  = blockIdx.x;
    if (bx < 256) {
        // 524288 float4 total; 2048 per block; 8 per thread
        #pragma unroll
        for (int g = 0; g < 8; ++g) {
            int fidx = bx * 2048 + g * 256 + tid;
            float4 a = reinterpret_cast<const float4*>(x)[fidx];
            uint2 w;
            w.x = pack2bf(a.x, a.y);
            w.y = pack2bf(a.z, a.w);
            reinterpret_cast<uint2*>(xb)[fidx] = w;
        }
    } else {
        const int mat = bx - 256;
        const float* W = (mat == 0) ? Wq : (mat == 1) ? Wk : Wv;
        const float* b = (mat == 0) ? bq : (mat == 1) ? bk : bv;
        const float s = (mat == 0) ? SCALE : 1.0f;
        for (int e = 0; e < 64; ++e) {
            int idx = e * 256 + tid;           // output index o*128+i
            int o = idx >> 7, i = idx & 127;
            Wt[mat * 16384 + idx] = f2bf(W[i * 128 + o] * s);
        }
        if (tid < 128) bprep[mat * 128 + tid] = b[tid] * s;
    }
}

// ---------------------------------------------------------------------------
// QKV GEMM, pure-register MFMA (no LDS). grid (128, 3), block 256 (4 waves).
// Wave covers 32 rows. mat<2: D[m=outchan][n=row] (A=Wt, B=xb) -> packed
// row-major q/k stores. mat==2: D[m=row][n=chan] (A=xb, B=Wt) -> packed vt.
// ---------------------------------------------------------------------------
__global__ __launch_bounds__(256)
void qkv_kernel(const unsigned short* __restrict__ xb,
                const unsigned short* __restrict__ Wt,
                const float* __restrict__ bprep,
                unsigned short* __restrict__ qo,
                unsigned short* __restrict__ ko,
                unsigned short* __restrict__ vt)
{
    const int tid  = threadIdx.x;
    const int wv   = tid >> 6;
    const int lane = tid & 63;
    const int lo   = lane & 15;
    const int quad = lane >> 4;
    const int mat  = blockIdx.y;
    const long rowbase = (long)blockIdx.x * 128 + wv * 32;

    const unsigned short* Wm = Wt + mat * 16384;
    const float* bm = bprep + mat * 128;

    // x fragments: xf[nt][ks] : row = rowbase + nt*16 + lo, k = ks*32 + quad*8
    bf16x8 xf[2][4];
    #pragma unroll
    for (int nt = 0; nt < 2; ++nt)
        #pragma unroll
        for (int ks = 0; ks < 4; ++ks)
            xf[nt][ks] = *reinterpret_cast<const bf16x8*>(
                &xb[(rowbase + nt * 16 + lo) * C + ks * 32 + quad * 8]);

    if (mat < 2) {
        f32x4 acc[8][2] = {};
        #pragma unroll
        for (int ks = 0; ks < 4; ++ks)
            #pragma unroll
            for (int mt = 0; mt < 8; ++mt) {
                bf16x8 wf = *reinterpret_cast<const bf16x8*>(
                    &Wm[(mt * 16 + lo) * C + ks * 32 + quad * 8]);
                #pragma unroll
                for (int nt = 0; nt < 2; ++nt)
                    acc[mt][nt] = __builtin_amdgcn_mfma_f32_16x16x32_bf16(
                        wf, xf[nt][ks], acc[mt][nt], 0, 0, 0);
            }
        unsigned short* out = (mat == 0) ? qo : ko;
        #pragma unroll
        for (int mt = 0; mt < 8; ++mt) {
            float4 bb = *reinterpret_cast<const float4*>(&bm[mt * 16 + quad * 4]);
            #pragma unroll
            for (int nt = 0; nt < 2; ++nt) {
                long row = rowbase + nt * 16 + lo;
                uint2 w;
                w.x = pack2bf(acc[mt][nt][0] + bb.x, acc[mt][nt][1] + bb.y);
                w.y = pack2bf(acc[mt][nt][2] + bb.z, acc[mt][nt][3] + bb.w);
                *reinterpret_cast<uint2*>(&out[row * C + mt * 16 + quad * 4]) = w;
            }
        }
    } else {
        f32x4 acc[2][8] = {};
        #pragma unroll
        for (int ks = 0; ks < 4; ++ks)
            #pragma unroll
            for (int ct = 0; ct < 8; ++ct) {
                bf16x8 wf = *reinterpret_cast<const bf16x8*>(
                    &Wm[(ct * 16 + lo) * C + ks * 32 + quad * 8]);
                #pragma unroll
                for (int mt = 0; mt < 2; ++mt)
                    acc[mt][ct] = __builtin_amdgcn_mfma_f32_16x16x32_bf16(
                        xf[mt][ks], wf, acc[mt][ct], 0, 0, 0);
            }
        const int b = (int)(rowbase >> 12);
        const int nbase = (int)(rowbase & (N - 1));
        #pragma unroll
        for (int ct = 0; ct < 8; ++ct) {
            int chan = ct * 16 + lo;
            float bb = bm[chan];
            #pragma unroll
            for (int mt = 0; mt < 2; ++mt) {
                int n0 = nbase + mt * 16 + quad * 4;
                uint2 w;
                w.x = pack2bf(acc[mt][ct][0] + bb, acc[mt][ct][1] + bb);
                w.y = pack2bf(acc[mt][ct][2] + bb, acc[mt][ct][3] + bb);
                *reinterpret_cast<uint2*>(
                    &vt[(size_t)b * (C * N) + (size_t)chan * N + n0]) = w;
            }
        }
    }
}

// ---------------------------------------------------------------------------
// Flash attention, S^T trick, split-K. grid (TOTROWS/128, 2), block 256.
// Wave owns 32 q-rows (2 n-tiles). S^T = K.Q^T so softmax is per-lane
// (col = q-row) + 2 shfls; P lands key-consecutive -> packed b64 LDS writes.
// Partials (unnormalized O bf16, m/l) written per split; combined later.
// ---------------------------------------------------------------------------
__global__ __launch_bounds__(256, 1)
void attn_kernel(const unsigned short* __restrict__ q,
                 const unsigned short* __restrict__ k,
                 const unsigned short* __restrict__ vt,
                 unsigned short* __restrict__ opart,
                 float2* __restrict__ ml)
{
    __shared__ __align__(16) unsigned short kl[BK * KSTR];      // 17408 B
    __shared__ __align__(16) unsigned short vl[C * VSTR];       // 18432 B
    __shared__ __align__(16) unsigned short pl[4 * 32 * PSTR];  // 18432 B
    __shared__ float albuf[4][32];

    const int tid  = threadIdx.x;
    const int wv   = tid >> 6;
    const int lane = tid & 63;
    const int lo   = lane & 15;
    const int quad = lane >> 4;

    const int q0    = blockIdx.x * 128;
    const int split = blockIdx.y;
    const int batch = q0 >> 12;
    const int koff  = split * (N / 2);

    const unsigned short* kb  = k  + ((size_t)batch * N + koff) * C;
    const unsigned short* vtb = vt + (size_t)batch * C * N + koff;
    unsigned short* plw = pl + wv * 32 * PSTR;

    // Q fragments (B operand): qf[nt][ks]: row = q0 + wv*32 + nt*16 + lo
    bf16x8 qf[2][4];
    #pragma unroll
    for (int nt = 0; nt < 2; ++nt)
        #pragma unroll
        for (int ks = 0; ks < 4; ++ks)
            qf[nt][ks] = *reinterpret_cast<const bf16x8*>(
                &q[(size_t)(q0 + wv * 32 + nt * 16 + lo) * C + ks * 32 + quad * 8]);

    // staging addresses (kt-invariant)
    uint4 kreg[4], vreg[4];
    int rK[4], cK[4], rV[4], jV[4];
    #pragma unroll
    for (int tt = 0; tt < 4; ++tt) {
        int idx = tt * 256 + tid;
        rK[tt] = idx >> 4;  cK[tt] = (idx & 15) * 8;
        rV[tt] = idx >> 3;  jV[tt] = (idx & 7) * 8;
    }
    // prefetch tile 0
    #pragma unroll
    for (int tt = 0; tt < 4; ++tt) {
        kreg[tt] = *reinterpret_cast<const uint4*>(&kb[(size_t)rK[tt] * C + cK[tt]]);
        vreg[tt] = *reinterpret_cast<const uint4*>(&vtb[(size_t)rV[tt] * N + jV[tt]]);
    }

    float m_i[2] = { -1e30f, -1e30f };
    float l_i[2] = { 0.f, 0.f };
    f32x4 ot[2][8] = {};   // [nt][ct]: rows nt*16+quad*4+reg, chan ct*16+lo

    constexpr int NIT = (N / 2) / BK;   // 32
    for (int kt = 0; kt < NIT; ++kt) {
        __syncthreads();   // prev iter's LDS reads complete
        #pragma unroll
        for (int tt = 0; tt < 4; ++tt) {
            *reinterpret_cast<uint4*>(&kl[rK[tt] * KSTR + cK[tt]]) = kreg[tt];
            *reinterpret_cast<uint4*>(&vl[rV[tt] * VSTR + jV[tt]]) = vreg[tt];
        }
        __syncthreads();
        if (kt + 1 < NIT) {   // prefetch next tile into regs (overlaps compute)
            const unsigned short* kn = kb  + (size_t)(kt + 1) * BK * C;
            const unsigned short* vn = vtb + (kt + 1) * BK;
            #pragma unroll
            for (int tt = 0; tt < 4; ++tt) {
                kreg[tt] = *reinterpret_cast<const uint4*>(&kn[(size_t)rK[tt] * C + cK[tt]]);
                vreg[tt] = *reinterpret_cast<const uint4*>(&vn[(size_t)rV[tt] * N + jV[tt]]);
            }
        }

        // ---- S^T = K . Q^T : st[mt][nt], key = mt*16+quad*4+reg, qrow = nt*16+lo
        f32x4 st[4][2] = {};
        #pragma unroll
        for (int ks = 0; ks < 4; ++ks)
            #pragma unroll
            for (int mt = 0; mt < 4; ++mt) {
                bf16x8 kf = *reinterpret_cast<const bf16x8*>(
                    &kl[(mt * 16 + lo) * KSTR + ks * 32 + quad * 8]);
                #pragma unroll
                for (int nt = 0; nt < 2; ++nt)
                    st[mt][nt] = __builtin_amdgcn_mfma_f32_16x16x32_bf16(
                        kf, qf[nt][ks], st[mt][nt], 0, 0, 0);
            }

        // ---- online softmax (per lane: col = qrow), P -> LDS packed ----
        #pragma unroll
        for (int nt = 0; nt < 2; ++nt) {
            float mx = -1e30f;
            #pragma unroll
            for (int mt = 0; mt < 4; ++mt)
                #pragma unroll
                for (int r = 0; r < 4; ++r)
                    mx = fmaxf(mx, st[mt][nt][r]);
            mx = fmaxf(mx, __shfl_xor(mx, 16));
            mx = fmaxf(mx, __shfl_xor(mx, 32));
            float mnew = fmaxf(m_i[nt], mx);
            float al   = __expf(m_i[nt] - mnew);
            m_i[nt] = mnew;
            float ps = 0.f;
            #pragma unroll
            for (int mt = 0; mt < 4; ++mt) {
                float p0 = __expf(st[mt][nt][0] - mnew);
                float p1 = __expf(st[mt][nt][1] - mnew);
                float p2 = __expf(st[mt][nt][2] - mnew);
                float p3 = __expf(st[mt][nt][3] - mnew);
                ps += (p0 + p1) + (p2 + p3);
                uint2 w;
                w.x = pack2bf(p0, p1);
                w.y = pack2bf(p2, p3);
                *reinterpret_cast<uint2*>(
                    &plw[(nt * 16 + lo) * PSTR + mt * 16 + quad * 4]) = w;
            }
            ps += __shfl_xor(ps, 16);
            ps += __shfl_xor(ps, 32);
            l_i[nt] = al * l_i[nt] + ps;
            if (quad == 0) albuf[wv][nt * 16 + lo] = al;
        }
        // intra-wave LDS write->read: in-order per wave, compiler waits lgkmcnt

        // ---- rescale O, then O += P.V ----
        #pragma unroll
        for (int nt = 0; nt < 2; ++nt) {
            f32x4 al4 = *reinterpret_cast<const f32x4*>(&albuf[wv][nt * 16 + quad * 4]);
            #pragma unroll
            for (int ct = 0; ct < 8; ++ct)
                #pragma unroll
                for (int r = 0; r < 4; ++r)
                    ot[nt][ct][r] *= al4[r];
        }
        #pragma unroll
        for (int ks2 = 0; ks2 < 2; ++ks2) {
            bf16x8 pf[2];
            #pragma unroll
            for (int nt = 0; nt < 2; ++nt)
                pf[nt] = *reinterpret_cast<const bf16x8*>(
                    &plw[(nt * 16 + lo) * PSTR + ks2 * 32 + quad * 8]);
            #pragma unroll
            for (int ct = 0; ct < 8; ++ct) {
                bf16x8 vf = *reinterpret_cast<const bf16x8*>(
                    &vl[(ct * 16 + lo) * VSTR + ks2 * 32 + quad * 8]);
                #pragma unroll
                for (int nt = 0; nt < 2; ++nt)
                    ot[nt][ct] = __builtin_amdgcn_mfma_f32_16x16x32_bf16(
                        pf[nt], vf, ot[nt][ct], 0, 0, 0);
            }
        }
    }

    // ---- write partials: unnormalized O (bf16), m/l per row ----
    unsigned short* ob = opart + (size_t)split * TOTROWS * C;
    #pragma unroll
    for (int nt = 0; nt < 2; ++nt) {
        #pragma unroll
        for (int r = 0; r < 4; ++r) {
            size_t rowg = q0 + wv * 32 + nt * 16 + quad * 4 + r;
            #pragma unroll
            for (int ct = 0; ct < 8; ++ct)
                ob[rowg * C + ct * 16 + lo] = f2bf(ot[nt][ct][r]);
        }
        if (quad == 0) {
            int rowg = q0 + wv * 32 + nt * 16 + lo;
            float2 v; v.x = m_i[nt]; v.y = l_i[nt];
            ml[(size_t)split * TOTROWS + rowg] = v;
        }
    }
}

// ---------------------------------------------------------------------------
// Combine splits + residual: out = x + (o0*w0 + o1*w1)/l
// ---------------------------------------------------------------------------
__global__ __launch_bounds__(256)
void combine_kernel(const float* __restrict__ x,
                    const unsigned short* __restrict__ opart,
                    const float2* __restrict__ ml,
                    float* __restrict__ out)
{
    int gid = blockIdx.x * 256 + threadIdx.x;     // TOTROWS*32
    int row = gid >> 5;
    int c4  = (gid & 31) * 4;
    float2 ml0 = ml[row];
    float2 ml1 = ml[TOTROWS + row];
    float M  = fmaxf(ml0.x, ml1.x);
    float w0 = __expf(ml0.x - M);
    float w1 = __expf(ml1.x - M);
    float inv = 1.0f / (ml0.y * w0 + ml1.y * w1);

    size_t idx = (size_t)row * C + c4;
    uint2 a = *reinterpret_cast<const uint2*>(&opart[idx]);
    uint2 b = *reinterpret_cast<const uint2*>(&opart[(size_t)TOTROWS * C + idx]);
    float4 xv = *reinterpret_cast<const float4*>(&x[idx]);
    float4 o;
    o.x = xv.x + (bf2f(a.x & 0xffff) * w0 + bf2f(b.x & 0xffff) * w1) * inv;
    o.y = xv.y + (bf2f(a.x >> 16)    * w0 + bf2f(b.x >> 16)    * w1) * inv;
    o.z = xv.z + (bf2f(a.y & 0xffff) * w0 + bf2f(b.y & 0xffff) * w1) * inv;
    o.w = xv.w + (bf2f(a.y >> 16)    * w0 + bf2f(b.y >> 16)    * w1) * inv;
    *reinterpret_cast<float4*>(&out[idx]) = o;
}

// ---------------------------------------------------------------------------
extern "C" void kernel_launch(void* const* d_in, const int* in_sizes, int n_in,
                              void* d_out, int out_size, void* d_ws, size_t ws_size,
                              hipStream_t stream)
{
    const float* x  = (const float*)d_in[0];
    const float* Wq = (const float*)d_in[1];
    const float* bq = (const float*)d_in[2];
    const float* Wk = (const float*)d_in[3];
    const float* bk = (const float*)d_in[4];
    const float* Wv = (const float*)d_in[5];
    const float* bv = (const float*)d_in[6];
    float* out = (float*)d_out;

    char* ws = (char*)d_ws;
    unsigned short* xb    = (unsigned short*)(ws);                 // 4 MB
    unsigned short* Wt    = (unsigned short*)(ws + 4194304);       // 96 KB
    float*          bprep = (float*)(ws + 4292608);                // 1.5 KB
    unsigned short* q     = (unsigned short*)(ws + 4294144);       // 4 MB
    unsigned short* k     = (unsigned short*)(ws + 8488448);       // 4 MB
    unsigned short* vt    = (unsigned short*)(ws + 12682752);      // 4 MB
    unsigned short* opart = (unsigned short*)(ws + 16877056);      // 8 MB
    float2*         ml    = (float2*)(ws + 25265664);              // 256 KB

    prep_kernel<<<259, 256, 0, stream>>>(x, Wq, bq, Wk, bk, Wv, bv, xb, Wt, bprep);
    qkv_kernel<<<dim3(TOTROWS / 128, 3), 256, 0, stream>>>(xb, Wt, bprep, q, k, vt);
    attn_kernel<<<dim3(TOTROWS / 128, 2), 256, 0, stream>>>(q, k, vt, opart, ml);
    combine_kernel<<<TOTROWS * 32 / 256, 256, 0, stream>>>(x, opart, ml, out);
}

// Round 4
// 243.157 us; speedup vs baseline: 1.1238x; 1.1238x over previous
//
#include <hip/hip_runtime.h>

// Problem constants: x [4, 64, 64, 128] fp32
constexpr int C       = 128;
constexpr int N       = 4096;
constexpr int BATCH   = 4;
constexpr int TOTROWS = BATCH * N;            // 16384
constexpr float SCALE = 0.08838834764831845f; // 1/sqrt(128)

constexpr int BK   = 64;     // keys per iteration
constexpr int PSTR = 72;     // P-tile LDS stride (bf16 elems): 144 B rows

typedef __attribute__((ext_vector_type(8))) short bf16x8;
typedef __attribute__((ext_vector_type(4))) float f32x4;

__device__ inline unsigned short f2bf(float f) {   // RNE float->bf16
    unsigned int u = __float_as_uint(f);
    return (unsigned short)((u + 0x7FFFu + ((u >> 16) & 1u)) >> 16);
}
__device__ inline unsigned int pack2bf(float a, float b) {
    return (unsigned int)f2bf(a) | ((unsigned int)f2bf(b) << 16);
}
__device__ inline float bf2f(unsigned short u) {
    return __uint_as_float((unsigned int)u << 16);
}

// ---------------------------------------------------------------------------
// prep: blocks 0..255 convert x fp32 -> xb bf16; blocks 256..258 build
// Wt[mat][o][i] = W[mat][i][o] (bf16, SCALE folded into mat 0) + bias fp32.
// ---------------------------------------------------------------------------
__global__ __launch_bounds__(256)
void prep_kernel(const float* __restrict__ x,
                 const float* __restrict__ Wq, const float* __restrict__ bq,
                 const float* __restrict__ Wk, const float* __restrict__ bk,
                 const float* __restrict__ Wv, const float* __restrict__ bv,
                 unsigned short* __restrict__ xb,
                 unsigned short* __restrict__ Wt,
                 float* __restrict__ bprep)
{
    const int tid = threadIdx.x;
    const int bx  = blockIdx.x;
    if (bx < 256) {
        #pragma unroll
        for (int g = 0; g < 8; ++g) {
            int fidx = bx * 2048 + g * 256 + tid;
            float4 a = reinterpret_cast<const float4*>(x)[fidx];
            uint2 w;
            w.x = pack2bf(a.x, a.y);
            w.y = pack2bf(a.z, a.w);
            reinterpret_cast<uint2*>(xb)[fidx] = w;
        }
    } else {
        const int mat = bx - 256;
        const float* W = (mat == 0) ? Wq : (mat == 1) ? Wk : Wv;
        const float* b = (mat == 0) ? bq : (mat == 1) ? bk : bv;
        const float s = (mat == 0) ? SCALE : 1.0f;
        for (int e = 0; e < 64; ++e) {
            int idx = e * 256 + tid;           // output index o*128+i
            int o = idx >> 7, i = idx & 127;
            Wt[mat * 16384 + idx] = f2bf(W[i * 128 + o] * s);
        }
        if (tid < 128) bprep[mat * 128 + tid] = b[tid] * s;
    }
}

// ---------------------------------------------------------------------------
// QKV GEMM, pure-register MFMA (no LDS). grid (128, 3), block 256 (4 waves).
// ---------------------------------------------------------------------------
__global__ __launch_bounds__(256)
void qkv_kernel(const unsigned short* __restrict__ xb,
                const unsigned short* __restrict__ Wt,
                const float* __restrict__ bprep,
                unsigned short* __restrict__ qo,
                unsigned short* __restrict__ ko,
                unsigned short* __restrict__ vt)
{
    const int tid  = threadIdx.x;
    const int wv   = tid >> 6;
    const int lane = tid & 63;
    const int lo   = lane & 15;
    const int quad = lane >> 4;
    const int mat  = blockIdx.y;
    const long rowbase = (long)blockIdx.x * 128 + wv * 32;

    const unsigned short* Wm = Wt + mat * 16384;
    const float* bm = bprep + mat * 128;

    bf16x8 xf[2][4];
    #pragma unroll
    for (int nt = 0; nt < 2; ++nt)
        #pragma unroll
        for (int ks = 0; ks < 4; ++ks)
            xf[nt][ks] = *reinterpret_cast<const bf16x8*>(
                &xb[(rowbase + nt * 16 + lo) * C + ks * 32 + quad * 8]);

    if (mat < 2) {
        f32x4 acc[8][2] = {};
        #pragma unroll
        for (int ks = 0; ks < 4; ++ks)
            #pragma unroll
            for (int mt = 0; mt < 8; ++mt) {
                bf16x8 wf = *reinterpret_cast<const bf16x8*>(
                    &Wm[(mt * 16 + lo) * C + ks * 32 + quad * 8]);
                #pragma unroll
                for (int nt = 0; nt < 2; ++nt)
                    acc[mt][nt] = __builtin_amdgcn_mfma_f32_16x16x32_bf16(
                        wf, xf[nt][ks], acc[mt][nt], 0, 0, 0);
            }
        unsigned short* out = (mat == 0) ? qo : ko;
        #pragma unroll
        for (int mt = 0; mt < 8; ++mt) {
            float4 bb = *reinterpret_cast<const float4*>(&bm[mt * 16 + quad * 4]);
            #pragma unroll
            for (int nt = 0; nt < 2; ++nt) {
                long row = rowbase + nt * 16 + lo;
                uint2 w;
                w.x = pack2bf(acc[mt][nt][0] + bb.x, acc[mt][nt][1] + bb.y);
                w.y = pack2bf(acc[mt][nt][2] + bb.z, acc[mt][nt][3] + bb.w);
                *reinterpret_cast<uint2*>(&out[row * C + mt * 16 + quad * 4]) = w;
            }
        }
    } else {
        f32x4 acc[2][8] = {};
        #pragma unroll
        for (int ks = 0; ks < 4; ++ks)
            #pragma unroll
            for (int ct = 0; ct < 8; ++ct) {
                bf16x8 wf = *reinterpret_cast<const bf16x8*>(
                    &Wm[(ct * 16 + lo) * C + ks * 32 + quad * 8]);
                #pragma unroll
                for (int mt = 0; mt < 2; ++mt)
                    acc[mt][ct] = __builtin_amdgcn_mfma_f32_16x16x32_bf16(
                        xf[mt][ks], wf, acc[mt][ct], 0, 0, 0);
            }
        const int b = (int)(rowbase >> 12);
        const int nbase = (int)(rowbase & (N - 1));
        #pragma unroll
        for (int ct = 0; ct < 8; ++ct) {
            int chan = ct * 16 + lo;
            float bb = bm[chan];
            #pragma unroll
            for (int mt = 0; mt < 2; ++mt) {
                int n0 = nbase + mt * 16 + quad * 4;
                uint2 w;
                w.x = pack2bf(acc[mt][ct][0] + bb, acc[mt][ct][1] + bb);
                w.y = pack2bf(acc[mt][ct][2] + bb, acc[mt][ct][3] + bb);
                *reinterpret_cast<uint2*>(
                    &vt[(size_t)b * (C * N) + (size_t)chan * N + n0]) = w;
            }
        }
    }
}

// ---------------------------------------------------------------------------
// Flash attention, barrier-free. grid (TOTROWS/128, nspl), block 256 (4 waves).
// Wave owns 32 q-rows; K and Vt fragments read DIRECTLY from global (L2/L3
// resident: 512 KB per (batch,split)). No __syncthreads anywhere: the only
// LDS use is the per-wave P buffer and the per-wave alpha broadcast, both
// intra-wave ordered (compiler lgkmcnt). S^T = K.Q^T per round 3 (verified):
// softmax per-lane (col=q-row) + 2 quad-shfls; P lands key-consecutive.
// ---------------------------------------------------------------------------
__global__ __launch_bounds__(256)
void attn_kernel(const unsigned short* __restrict__ q,
                 const unsigned short* __restrict__ k,
                 const unsigned short* __restrict__ vt,
                 unsigned short* __restrict__ opart,
                 float2* __restrict__ ml)
{
    __shared__ __align__(16) unsigned short pl[4 * 32 * PSTR];  // 18432 B
    __shared__ float albuf[4][32];

    const int tid  = threadIdx.x;
    const int wv   = tid >> 6;
    const int lane = tid & 63;
    const int lo   = lane & 15;
    const int quad = lane >> 4;

    const int nspl  = (int)gridDim.y;
    const int NIT   = (N / nspl) / BK;
    const int q0    = blockIdx.x * 128;
    const int split = blockIdx.y;
    const int batch = q0 >> 12;
    const int koff  = split * (N / nspl);

    const unsigned short* kb  = k  + ((size_t)batch * N + koff) * C;
    const unsigned short* vtb = vt + (size_t)batch * C * N + koff;
    unsigned short* plw = pl + wv * 32 * PSTR;

    // Q fragments (B operand): qf[nt][ks]: row = q0 + wv*32 + nt*16 + lo
    bf16x8 qf[2][4];
    #pragma unroll
    for (int nt = 0; nt < 2; ++nt)
        #pragma unroll
        for (int ks = 0; ks < 4; ++ks)
            qf[nt][ks] = *reinterpret_cast<const bf16x8*>(
                &q[(size_t)(q0 + wv * 32 + nt * 16 + lo) * C + ks * 32 + quad * 8]);

    float m_i[2] = { -1e30f, -1e30f };
    float l_i[2] = { 0.f, 0.f };
    f32x4 ot[2][8] = {};   // [nt][ct]: rows nt*16+quad*4+reg, chan ct*16+lo

    for (int kt = 0; kt < NIT; ++kt) {
        const unsigned short* kt_base = kb  + (size_t)kt * BK * C;
        const unsigned short* vt_base = vtb + kt * BK;

        // ---- S^T = K . Q^T : st[mt][nt], key = mt*16+quad*4+reg, qrow = nt*16+lo
        f32x4 st[4][2] = {};
        #pragma unroll
        for (int ks = 0; ks < 4; ++ks)
            #pragma unroll
            for (int mt = 0; mt < 4; ++mt) {
                bf16x8 kf = *reinterpret_cast<const bf16x8*>(
                    &kt_base[(size_t)(mt * 16 + lo) * C + ks * 32 + quad * 8]);
                #pragma unroll
                for (int nt = 0; nt < 2; ++nt)
                    st[mt][nt] = __builtin_amdgcn_mfma_f32_16x16x32_bf16(
                        kf, qf[nt][ks], st[mt][nt], 0, 0, 0);
            }

        // ---- online softmax (per lane: col = qrow), P -> per-wave LDS ----
        #pragma unroll
        for (int nt = 0; nt < 2; ++nt) {
            float mx = -1e30f;
            #pragma unroll
            for (int mt = 0; mt < 4; ++mt)
                #pragma unroll
                for (int r = 0; r < 4; ++r)
                    mx = fmaxf(mx, st[mt][nt][r]);
            mx = fmaxf(mx, __shfl_xor(mx, 16));
            mx = fmaxf(mx, __shfl_xor(mx, 32));
            float mnew = fmaxf(m_i[nt], mx);
            float al   = __expf(m_i[nt] - mnew);
            m_i[nt] = mnew;
            float ps = 0.f;
            #pragma unroll
            for (int mt = 0; mt < 4; ++mt) {
                float p0 = __expf(st[mt][nt][0] - mnew);
                float p1 = __expf(st[mt][nt][1] - mnew);
                float p2 = __expf(st[mt][nt][2] - mnew);
                float p3 = __expf(st[mt][nt][3] - mnew);
                ps += (p0 + p1) + (p2 + p3);
                uint2 w;
                w.x = pack2bf(p0, p1);
                w.y = pack2bf(p2, p3);
                *reinterpret_cast<uint2*>(
                    &plw[(nt * 16 + lo) * PSTR + mt * 16 + quad * 4]) = w;
            }
            ps += __shfl_xor(ps, 16);
            ps += __shfl_xor(ps, 32);
            l_i[nt] = al * l_i[nt] + ps;
            if (quad == 0) albuf[wv][nt * 16 + lo] = al;
        }

        // ---- rescale O, then O += P.V (V fragments direct from global) ----
        #pragma unroll
        for (int nt = 0; nt < 2; ++nt) {
            f32x4 al4 = *reinterpret_cast<const f32x4*>(&albuf[wv][nt * 16 + quad * 4]);
            #pragma unroll
            for (int ct = 0; ct < 8; ++ct)
                #pragma unroll
                for (int r = 0; r < 4; ++r)
                    ot[nt][ct][r] *= al4[r];
        }
        #pragma unroll
        for (int ks2 = 0; ks2 < 2; ++ks2) {
            bf16x8 pf[2];
            #pragma unroll
            for (int nt = 0; nt < 2; ++nt)
                pf[nt] = *reinterpret_cast<const bf16x8*>(
                    &plw[(nt * 16 + lo) * PSTR + ks2 * 32 + quad * 8]);
            #pragma unroll
            for (int ct = 0; ct < 8; ++ct) {
                bf16x8 vf = *reinterpret_cast<const bf16x8*>(
                    &vt_base[(size_t)(ct * 16 + lo) * N + ks2 * 32 + quad * 8]);
                #pragma unroll
                for (int nt = 0; nt < 2; ++nt)
                    ot[nt][ct] = __builtin_amdgcn_mfma_f32_16x16x32_bf16(
                        pf[nt], vf, ot[nt][ct], 0, 0, 0);
            }
        }
    }

    // ---- write partials: unnormalized O (bf16), m/l per row ----
    unsigned short* ob = opart + (size_t)split * TOTROWS * C;
    #pragma unroll
    for (int nt = 0; nt < 2; ++nt) {
        #pragma unroll
        for (int r = 0; r < 4; ++r) {
            size_t rowg = q0 + wv * 32 + nt * 16 + quad * 4 + r;
            #pragma unroll
            for (int ct = 0; ct < 8; ++ct)
                ob[rowg * C + ct * 16 + lo] = f2bf(ot[nt][ct][r]);
        }
        if (quad == 0) {
            int rowg = q0 + wv * 32 + nt * 16 + lo;
            float2 v; v.x = m_i[nt]; v.y = l_i[nt];
            ml[(size_t)split * TOTROWS + rowg] = v;
        }
    }
}

// ---------------------------------------------------------------------------
// Combine nspl splits + residual: out = x + (sum_j w_j O_j) / (sum_j w_j l_j)
// ---------------------------------------------------------------------------
__global__ __launch_bounds__(256)
void combine_kernel(const float* __restrict__ x,
                    const unsigned short* __restrict__ opart,
                    const float2* __restrict__ ml,
                    float* __restrict__ out, int nspl)
{
    int gid = blockIdx.x * 256 + threadIdx.x;     // TOTROWS*32
    int row = gid >> 5;
    int c4  = (gid & 31) * 4;

    float2 mlv[4];
    for (int j = 0; j < nspl; ++j) mlv[j] = ml[(size_t)j * TOTROWS + row];
    float M = mlv[0].x;
    for (int j = 1; j < nspl; ++j) M = fmaxf(M, mlv[j].x);
    float wgt[4]; float denom = 0.f;
    for (int j = 0; j < nspl; ++j) {
        wgt[j] = __expf(mlv[j].x - M);
        denom += mlv[j].y * wgt[j];
    }
    float inv = 1.0f / denom;

    size_t idx = (size_t)row * C + c4;
    float a0 = 0.f, a1 = 0.f, a2 = 0.f, a3 = 0.f;
    for (int j = 0; j < nspl; ++j) {
        uint2 o = *reinterpret_cast<const uint2*>(&opart[(size_t)j * TOTROWS * C + idx]);
        a0 += wgt[j] * bf2f(o.x & 0xffff);
        a1 += wgt[j] * bf2f(o.x >> 16);
        a2 += wgt[j] * bf2f(o.y & 0xffff);
        a3 += wgt[j] * bf2f(o.y >> 16);
    }
    float4 xv = *reinterpret_cast<const float4*>(&x[idx]);
    float4 o;
    o.x = xv.x + a0 * inv;
    o.y = xv.y + a1 * inv;
    o.z = xv.z + a2 * inv;
    o.w = xv.w + a3 * inv;
    *reinterpret_cast<float4*>(&out[idx]) = o;
}

// ---------------------------------------------------------------------------
extern "C" void kernel_launch(void* const* d_in, const int* in_sizes, int n_in,
                              void* d_out, int out_size, void* d_ws, size_t ws_size,
                              hipStream_t stream)
{
    const float* x  = (const float*)d_in[0];
    const float* Wq = (const float*)d_in[1];
    const float* bq = (const float*)d_in[2];
    const float* Wk = (const float*)d_in[3];
    const float* bk = (const float*)d_in[4];
    const float* Wv = (const float*)d_in[5];
    const float* bv = (const float*)d_in[6];
    float* out = (float*)d_out;

    // nspl=4 needs ~28.7 MB of ws; fall back to 2 (~20.7 MB, proven) if small.
    // ws_size is launch-invariant, so this branch is identical on every call.
    const int nspl = (ws_size >= ((size_t)31 << 20)) ? 4 : 2;

    const size_t SPLIT_BYTES = (size_t)TOTROWS * C * 2;   // 4 MB
    char* ws = (char*)d_ws;
    unsigned short* opart = (unsigned short*)ws;                  // nspl*4 MB
    unsigned short* xb    = (unsigned short*)ws;                  // 4 MB, aliases opart (dead before attn)
    char* base = ws + (size_t)nspl * SPLIT_BYTES;
    unsigned short* q     = (unsigned short*)(base);              // 4 MB
    unsigned short* k     = (unsigned short*)(base + SPLIT_BYTES);        // 4 MB
    unsigned short* vt    = (unsigned short*)(base + 2 * SPLIT_BYTES);    // 4 MB
    unsigned short* Wt    = (unsigned short*)(base + 3 * SPLIT_BYTES);    // 96 KB
    float*          bprep = (float*)(base + 3 * SPLIT_BYTES + 131072);    // 1.5 KB
    float2*         ml    = (float2*)(base + 3 * SPLIT_BYTES + 135168);   // nspl*128 KB

    prep_kernel<<<259, 256, 0, stream>>>(x, Wq, bq, Wk, bk, Wv, bv, xb, Wt, bprep);
    qkv_kernel<<<dim3(TOTROWS / 128, 3), 256, 0, stream>>>(xb, Wt, bprep, q, k, vt);
    attn_kernel<<<dim3(TOTROWS / 128, nspl), 256, 0, stream>>>(q, k, vt, opart, ml);
    combine_kernel<<<TOTROWS * 32 / 256, 256, 0, stream>>>(x, opart, ml, out, nspl);
}

// Round 5
// 225.018 us; speedup vs baseline: 1.2144x; 1.0806x over previous
//
#include <hip/hip_runtime.h>

// Problem constants: x [4, 64, 64, 128] fp32
constexpr int C       = 128;
constexpr int N       = 4096;
constexpr int BATCH   = 4;
constexpr int TOTROWS = BATCH * N;            // 16384
constexpr float SCALE = 0.08838834764831845f; // 1/sqrt(128)

constexpr int BK   = 64;     // keys per iteration
constexpr int PSTR = 72;     // P-tile LDS stride (bf16 elems): 144 B rows

typedef __attribute__((ext_vector_type(8))) short bf16x8;
typedef __attribute__((ext_vector_type(4))) float f32x4;

__device__ inline unsigned short f2bf(float f) {   // RNE float->bf16
    unsigned int u = __float_as_uint(f);
    return (unsigned short)((u + 0x7FFFu + ((u >> 16) & 1u)) >> 16);
}
__device__ inline unsigned int pack2bf(float a, float b) {
    return (unsigned int)f2bf(a) | ((unsigned int)f2bf(b) << 16);
}
__device__ inline float bf2f(unsigned short u) {
    return __uint_as_float((unsigned int)u << 16);
}

// ---------------------------------------------------------------------------
// wprep: 3 blocks. Coalesced W read -> LDS transpose -> coalesced Wt write.
// Wt[mat][o][i] = W[mat][i][o] (bf16, SCALE folded into mat 0), bias fp32.
// ---------------------------------------------------------------------------
__global__ __launch_bounds__(256)
void wprep_kernel(const float* __restrict__ Wq, const float* __restrict__ bq,
                  const float* __restrict__ Wk, const float* __restrict__ bk,
                  const float* __restrict__ Wv, const float* __restrict__ bv,
                  unsigned short* __restrict__ Wt,
                  float* __restrict__ bprep)
{
    constexpr int TS = 136;                      // 272 B rows: 16B-aligned
    __shared__ __align__(16) unsigned short wl[128 * TS];
    const int tid = threadIdx.x;
    const int mat = blockIdx.x;
    const float* W = (mat == 0) ? Wq : (mat == 1) ? Wk : Wv;
    const float* b = (mat == 0) ? bq : (mat == 1) ? bk : bv;
    const float s  = (mat == 0) ? SCALE : 1.0f;

    #pragma unroll
    for (int g = 0; g < 16; ++g) {
        int idx = g * 256 + tid;                 // 0..4095 float4s of W
        int i = idx >> 5, c4 = (idx & 31) * 4;
        float4 a = *reinterpret_cast<const float4*>(&W[i * 128 + c4]);
        wl[(c4 + 0) * TS + i] = f2bf(a.x * s);
        wl[(c4 + 1) * TS + i] = f2bf(a.y * s);
        wl[(c4 + 2) * TS + i] = f2bf(a.z * s);
        wl[(c4 + 3) * TS + i] = f2bf(a.w * s);
    }
    __syncthreads();
    #pragma unroll
    for (int g = 0; g < 8; ++g) {
        int idx = g * 256 + tid;                 // 0..2047 uint4s of Wt
        int o = idx >> 4, off = (idx & 15) * 8;
        *reinterpret_cast<uint4*>(&Wt[mat * 16384 + o * 128 + off]) =
            *reinterpret_cast<const uint4*>(&wl[o * TS + off]);
    }
    if (tid < 128) bprep[mat * 128 + tid] = b[tid] * s;
}

// ---------------------------------------------------------------------------
// QKV GEMM, pure-register MFMA, fused fp32->bf16 conversion of x.
// grid (128, 3), block 256 (4 waves). vt stored TILED: vt[b][n/64][c][n%64].
// ---------------------------------------------------------------------------
__global__ __launch_bounds__(256)
void qkv_kernel(const float* __restrict__ x,
                const unsigned short* __restrict__ Wt,
                const float* __restrict__ bprep,
                unsigned short* __restrict__ qo,
                unsigned short* __restrict__ ko,
                unsigned short* __restrict__ vt)
{
    const int tid  = threadIdx.x;
    const int wv   = tid >> 6;
    const int lane = tid & 63;
    const int lo   = lane & 15;
    const int quad = lane >> 4;
    const int mat  = blockIdx.y;
    const long rowbase = (long)blockIdx.x * 128 + wv * 32;

    const unsigned short* Wm = Wt + mat * 16384;
    const float* bm = bprep + mat * 128;

    // x fragments, converted fp32 -> bf16 in registers
    bf16x8 xf[2][4];
    #pragma unroll
    for (int nt = 0; nt < 2; ++nt) {
        const float4* xr = reinterpret_cast<const float4*>(
            &x[(rowbase + nt * 16 + lo) * C]);
        #pragma unroll
        for (int ks = 0; ks < 4; ++ks) {
            float4 a  = xr[ks * 8 + quad * 2];
            float4 b2 = xr[ks * 8 + quad * 2 + 1];
            union { bf16x8 v; unsigned int u[4]; } cv;
            cv.u[0] = pack2bf(a.x, a.y);
            cv.u[1] = pack2bf(a.z, a.w);
            cv.u[2] = pack2bf(b2.x, b2.y);
            cv.u[3] = pack2bf(b2.z, b2.w);
            xf[nt][ks] = cv.v;
        }
    }

    if (mat < 2) {
        f32x4 acc[8][2] = {};
        #pragma unroll
        for (int ks = 0; ks < 4; ++ks)
            #pragma unroll
            for (int mt = 0; mt < 8; ++mt) {
                bf16x8 wf = *reinterpret_cast<const bf16x8*>(
                    &Wm[(mt * 16 + lo) * C + ks * 32 + quad * 8]);
                #pragma unroll
                for (int nt = 0; nt < 2; ++nt)
                    acc[mt][nt] = __builtin_amdgcn_mfma_f32_16x16x32_bf16(
                        wf, xf[nt][ks], acc[mt][nt], 0, 0, 0);
            }
        unsigned short* out = (mat == 0) ? qo : ko;
        #pragma unroll
        for (int mt = 0; mt < 8; ++mt) {
            float4 bb = *reinterpret_cast<const float4*>(&bm[mt * 16 + quad * 4]);
            #pragma unroll
            for (int nt = 0; nt < 2; ++nt) {
                long row = rowbase + nt * 16 + lo;
                uint2 w;
                w.x = pack2bf(acc[mt][nt][0] + bb.x, acc[mt][nt][1] + bb.y);
                w.y = pack2bf(acc[mt][nt][2] + bb.z, acc[mt][nt][3] + bb.w);
                *reinterpret_cast<uint2*>(&out[row * C + mt * 16 + quad * 4]) = w;
            }
        }
    } else {
        f32x4 acc[2][8] = {};
        #pragma unroll
        for (int ks = 0; ks < 4; ++ks)
            #pragma unroll
            for (int ct = 0; ct < 8; ++ct) {
                bf16x8 wf = *reinterpret_cast<const bf16x8*>(
                    &Wm[(ct * 16 + lo) * C + ks * 32 + quad * 8]);
                #pragma unroll
                for (int mt = 0; mt < 2; ++mt)
                    acc[mt][ct] = __builtin_amdgcn_mfma_f32_16x16x32_bf16(
                        xf[mt][ks], wf, acc[mt][ct], 0, 0, 0);
            }
        const int b = (int)(rowbase >> 12);
        const int nbase = (int)(rowbase & (N - 1));
        #pragma unroll
        for (int ct = 0; ct < 8; ++ct) {
            int chan = ct * 16 + lo;
            float bb = bm[chan];
            #pragma unroll
            for (int mt = 0; mt < 2; ++mt) {
                int n0   = nbase + mt * 16 + quad * 4;
                int nblk = n0 >> 6;
                uint2 w;
                w.x = pack2bf(acc[mt][ct][0] + bb, acc[mt][ct][1] + bb);
                w.y = pack2bf(acc[mt][ct][2] + bb, acc[mt][ct][3] + bb);
                *reinterpret_cast<uint2*>(
                    &vt[(((size_t)b * 64 + nblk) * 128 + chan) * 64 + (n0 & 63)]) = w;
            }
        }
    }
}

// ---------------------------------------------------------------------------
// Flash attention, barrier-free, XCD-swizzled. 1-D grid of 128*nspl blocks,
// block 256 (4 waves, wave owns 32 q-rows). Decode keeps id%8 == f(batch,
// split-parity) so each XCD (round-robin %8 heuristic) sees ONE batch and 2
// splits -> K/V+Q working set ~2 MB, L2-resident. K fragments read direct
// from global (row-major, 16x64B/instr); V from TILED vt (lane stride 128B).
// V fragments early-issued into registers under the softmax phase.
// ---------------------------------------------------------------------------
__global__ __launch_bounds__(256, 2)
void attn_kernel(const unsigned short* __restrict__ q,
                 const unsigned short* __restrict__ k,
                 const unsigned short* __restrict__ vt,
                 unsigned short* __restrict__ opart,
                 float2* __restrict__ ml)
{
    __shared__ __align__(16) unsigned short pl[4 * 32 * PSTR];  // 18432 B
    __shared__ float albuf[4][32];

    const int tid  = threadIdx.x;
    const int wv   = tid >> 6;
    const int lane = tid & 63;
    const int lo   = lane & 15;
    const int quad = lane >> 4;

    const int nspl = (int)(gridDim.x >> 7);      // 128 blocks per (batch,split)... per qtile set
    const int id   = blockIdx.x;
    int b, sl, qt;
    if (nspl == 4) {         // id%8 = b*2 + (sl&1)
        b  = (id >> 1) & 3;
        sl = (id & 1) | (((id >> 3) & 1) << 1);
        qt = id >> 4;
    } else {                 // nspl == 2: id%8 = b*2 + sl
        b  = (id >> 1) & 3;
        sl = id & 1;
        qt = id >> 3;
    }
    const int NIT  = (N / nspl) / BK;
    const int koff = sl * (N / nspl);

    const size_t qrow0 = (size_t)b * N + qt * 128;
    const unsigned short* kb  = k  + ((size_t)b * N + koff) * C;
    const unsigned short* vtb = vt + ((size_t)b * 64 + (koff >> 6)) * (size_t)(128 * 64);
    unsigned short* plw = pl + wv * 32 * PSTR;

    // Q fragments (B operand): qf[nt][ks]: row = qrow0 + wv*32 + nt*16 + lo
    bf16x8 qf[2][4];
    #pragma unroll
    for (int nt = 0; nt < 2; ++nt)
        #pragma unroll
        for (int ks = 0; ks < 4; ++ks)
            qf[nt][ks] = *reinterpret_cast<const bf16x8*>(
                &q[(qrow0 + wv * 32 + nt * 16 + lo) * C + ks * 32 + quad * 8]);

    float m_i[2] = { -1e30f, -1e30f };
    float l_i[2] = { 0.f, 0.f };
    f32x4 ot[2][8] = {};   // [nt][ct]: rows nt*16+quad*4+reg, chan ct*16+lo

    for (int kt = 0; kt < NIT; ++kt) {
        const unsigned short* kt_base = kb  + (size_t)kt * BK * C;
        const unsigned short* vt_base = vtb + (size_t)kt * (128 * 64);

        // ---- S^T = K . Q^T : st[mt][nt], key = mt*16+quad*4+reg, qrow = nt*16+lo
        f32x4 st[4][2] = {};
        #pragma unroll
        for (int ks = 0; ks < 4; ++ks)
            #pragma unroll
            for (int mt = 0; mt < 4; ++mt) {
                bf16x8 kf = *reinterpret_cast<const bf16x8*>(
                    &kt_base[(size_t)(mt * 16 + lo) * C + ks * 32 + quad * 8]);
                #pragma unroll
                for (int nt = 0; nt < 2; ++nt)
                    st[mt][nt] = __builtin_amdgcn_mfma_f32_16x16x32_bf16(
                        kf, qf[nt][ks], st[mt][nt], 0, 0, 0);
            }

        // ---- early-issue V fragments (in flight during softmax) ----
        bf16x8 vfr[2][8];
        #pragma unroll
        for (int ks2 = 0; ks2 < 2; ++ks2)
            #pragma unroll
            for (int ct = 0; ct < 8; ++ct)
                vfr[ks2][ct] = *reinterpret_cast<const bf16x8*>(
                    &vt_base[(ct * 16 + lo) * 64 + ks2 * 32 + quad * 8]);

        // ---- online softmax (per lane: col = qrow), P -> per-wave LDS ----
        #pragma unroll
        for (int nt = 0; nt < 2; ++nt) {
            float mx = -1e30f;
            #pragma unroll
            for (int mt = 0; mt < 4; ++mt)
                #pragma unroll
                for (int r = 0; r < 4; ++r)
                    mx = fmaxf(mx, st[mt][nt][r]);
            mx = fmaxf(mx, __shfl_xor(mx, 16));
            mx = fmaxf(mx, __shfl_xor(mx, 32));
            float mnew = fmaxf(m_i[nt], mx);
            float al   = __expf(m_i[nt] - mnew);
            m_i[nt] = mnew;
            float ps = 0.f;
            #pragma unroll
            for (int mt = 0; mt < 4; ++mt) {
                float p0 = __expf(st[mt][nt][0] - mnew);
                float p1 = __expf(st[mt][nt][1] - mnew);
                float p2 = __expf(st[mt][nt][2] - mnew);
                float p3 = __expf(st[mt][nt][3] - mnew);
                ps += (p0 + p1) + (p2 + p3);
                uint2 w;
                w.x = pack2bf(p0, p1);
                w.y = pack2bf(p2, p3);
                *reinterpret_cast<uint2*>(
                    &plw[(nt * 16 + lo) * PSTR + mt * 16 + quad * 4]) = w;
            }
            ps += __shfl_xor(ps, 16);
            ps += __shfl_xor(ps, 32);
            l_i[nt] = al * l_i[nt] + ps;
            if (quad == 0) albuf[wv][nt * 16 + lo] = al;
        }

        // ---- rescale O, then O += P.V ----
        #pragma unroll
        for (int nt = 0; nt < 2; ++nt) {
            f32x4 al4 = *reinterpret_cast<const f32x4*>(&albuf[wv][nt * 16 + quad * 4]);
            #pragma unroll
            for (int ct = 0; ct < 8; ++ct)
                #pragma unroll
                for (int r = 0; r < 4; ++r)
                    ot[nt][ct][r] *= al4[r];
        }
        #pragma unroll
        for (int ks2 = 0; ks2 < 2; ++ks2) {
            bf16x8 pf[2];
            #pragma unroll
            for (int nt = 0; nt < 2; ++nt)
                pf[nt] = *reinterpret_cast<const bf16x8*>(
                    &plw[(nt * 16 + lo) * PSTR + ks2 * 32 + quad * 8]);
            #pragma unroll
            for (int ct = 0; ct < 8; ++ct)
                #pragma unroll
                for (int nt = 0; nt < 2; ++nt)
                    ot[nt][ct] = __builtin_amdgcn_mfma_f32_16x16x32_bf16(
                        pf[nt], vfr[ks2][ct], ot[nt][ct], 0, 0, 0);
        }
    }

    // ---- write partials: unnormalized O (bf16), m/l per row ----
    unsigned short* ob = opart + (size_t)sl * TOTROWS * C;
    #pragma unroll
    for (int nt = 0; nt < 2; ++nt) {
        #pragma unroll
        for (int r = 0; r < 4; ++r) {
            size_t rowg = qrow0 + wv * 32 + nt * 16 + quad * 4 + r;
            #pragma unroll
            for (int ct = 0; ct < 8; ++ct)
                ob[rowg * C + ct * 16 + lo] = f2bf(ot[nt][ct][r]);
        }
        if (quad == 0) {
            size_t rowg = qrow0 + wv * 32 + nt * 16 + lo;
            float2 v; v.x = m_i[nt]; v.y = l_i[nt];
            ml[(size_t)sl * TOTROWS + rowg] = v;
        }
    }
}

// ---------------------------------------------------------------------------
// Combine nspl splits + residual: out = x + (sum_j w_j O_j) / (sum_j w_j l_j)
// ---------------------------------------------------------------------------
__global__ __launch_bounds__(256)
void combine_kernel(const float* __restrict__ x,
                    const unsigned short* __restrict__ opart,
                    const float2* __restrict__ ml,
                    float* __restrict__ out, int nspl)
{
    int gid = blockIdx.x * 256 + threadIdx.x;     // TOTROWS*32
    int row = gid >> 5;
    int c4  = (gid & 31) * 4;

    float2 mlv[4];
    for (int j = 0; j < nspl; ++j) mlv[j] = ml[(size_t)j * TOTROWS + row];
    float M = mlv[0].x;
    for (int j = 1; j < nspl; ++j) M = fmaxf(M, mlv[j].x);
    float wgt[4]; float denom = 0.f;
    for (int j = 0; j < nspl; ++j) {
        wgt[j] = __expf(mlv[j].x - M);
        denom += mlv[j].y * wgt[j];
    }
    float inv = 1.0f / denom;

    size_t idx = (size_t)row * C + c4;
    float a0 = 0.f, a1 = 0.f, a2 = 0.f, a3 = 0.f;
    for (int j = 0; j < nspl; ++j) {
        uint2 o = *reinterpret_cast<const uint2*>(&opart[(size_t)j * TOTROWS * C + idx]);
        a0 += wgt[j] * bf2f(o.x & 0xffff);
        a1 += wgt[j] * bf2f(o.x >> 16);
        a2 += wgt[j] * bf2f(o.y & 0xffff);
        a3 += wgt[j] * bf2f(o.y >> 16);
    }
    float4 xv = *reinterpret_cast<const float4*>(&x[idx]);
    float4 o;
    o.x = xv.x + a0 * inv;
    o.y = xv.y + a1 * inv;
    o.z = xv.z + a2 * inv;
    o.w = xv.w + a3 * inv;
    *reinterpret_cast<float4*>(&out[idx]) = o;
}

// ---------------------------------------------------------------------------
extern "C" void kernel_launch(void* const* d_in, const int* in_sizes, int n_in,
                              void* d_out, int out_size, void* d_ws, size_t ws_size,
                              hipStream_t stream)
{
    const float* x  = (const float*)d_in[0];
    const float* Wq = (const float*)d_in[1];
    const float* bq = (const float*)d_in[2];
    const float* Wk = (const float*)d_in[3];
    const float* bk = (const float*)d_in[4];
    const float* Wv = (const float*)d_in[5];
    const float* bv = (const float*)d_in[6];
    float* out = (float*)d_out;

    // nspl=4 needs ~28.4 MB of ws; fall back to 2 if the workspace is small.
    const int nspl = (ws_size >= ((size_t)31 << 20)) ? 4 : 2;

    const size_t SPLIT_BYTES = (size_t)TOTROWS * C * 2;   // 4 MB
    char* ws = (char*)d_ws;
    unsigned short* opart = (unsigned short*)ws;                  // nspl*4 MB
    char* base = ws + (size_t)nspl * SPLIT_BYTES;
    unsigned short* q     = (unsigned short*)(base);                      // 4 MB
    unsigned short* k     = (unsigned short*)(base + SPLIT_BYTES);        // 4 MB
    unsigned short* vt    = (unsigned short*)(base + 2 * SPLIT_BYTES);    // 4 MB (tiled)
    unsigned short* Wt    = (unsigned short*)(base + 3 * SPLIT_BYTES);    // 96 KB
    float*          bprep = (float*)(base + 3 * SPLIT_BYTES + 131072);    // 1.5 KB
    float2*         ml    = (float2*)(base + 3 * SPLIT_BYTES + 135168);   // nspl*128 KB

    wprep_kernel<<<3, 256, 0, stream>>>(Wq, bq, Wk, bk, Wv, bv, Wt, bprep);
    qkv_kernel<<<dim3(TOTROWS / 128, 3), 256, 0, stream>>>(x, Wt, bprep, q, k, vt);
    attn_kernel<<<128 * nspl, 256, 0, stream>>>(q, k, vt, opart, ml);
    combine_kernel<<<TOTROWS * 32 / 256, 256, 0, stream>>>(x, opart, ml, out, nspl);
}